// Round 1
// baseline (2899.774 us; speedup 1.0000x reference)
//
#include <hip/hip_runtime.h>
#include <math.h>

// Problem constants (from reference)
#define B_ 32
#define T_ 1024
#define C_ 768
#define M_ (B_ * T_)   // 32768 rows

// ---------------------------------------------------------------------------
// GEMM: out[m][n] = sum_c A'[m][c] * W[n][c]   (W is [N=768][K=768] row-major,
// i.e. einsum 'btc,oc->bto').  MIX=1 applies the RWKV time-shift mix to A on
// the fly: A'[m][c] = x[m][c]*tm[c] + x[m-1][c]*(1-tm[c])  (x[-1] = 0 at t==0)
// ---------------------------------------------------------------------------
#define BM 64
#define BN 64
#define BK 16

template <int MIX>
__global__ __launch_bounds__(256) void gemm_bt(const float* A,
                                               const float* __restrict__ W,
                                               const float* __restrict__ tmix,
                                               float* out) {
  __shared__ float As[BK][BM];
  __shared__ float Ws[BK][BN];

  const int tid = threadIdx.x;
  const int m0 = blockIdx.x * BM;
  const int n0 = blockIdx.y * BN;
  const int lrow = tid >> 2;        // 0..63  (tile row loaded by this thread)
  const int lk = (tid & 3) << 2;    // 0,4,8,12 (k-chunk within BK)
  const int ty = tid >> 4;          // 0..15
  const int tx = tid & 15;          // 0..15

  float acc[4][4] = {};

  for (int k0 = 0; k0 < C_; k0 += BK) {
    // ---- stage A tile (with optional time-shift mix) ----
    {
      const int m = m0 + lrow;
      const float* ap = A + (size_t)m * C_ + (k0 + lk);
      float4 a = *(const float4*)ap;
      if (MIX) {
        float4 xp = make_float4(0.f, 0.f, 0.f, 0.f);
        if ((m & (T_ - 1)) != 0) xp = *(const float4*)(ap - C_);
        const float4 tm = *(const float4*)(tmix + k0 + lk);
        a.x = a.x * tm.x + xp.x * (1.f - tm.x);
        a.y = a.y * tm.y + xp.y * (1.f - tm.y);
        a.z = a.z * tm.z + xp.z * (1.f - tm.z);
        a.w = a.w * tm.w + xp.w * (1.f - tm.w);
      }
      As[lk + 0][lrow] = a.x;
      As[lk + 1][lrow] = a.y;
      As[lk + 2][lrow] = a.z;
      As[lk + 3][lrow] = a.w;
    }
    // ---- stage W tile ----
    {
      const float* wp = W + (size_t)(n0 + lrow) * C_ + (k0 + lk);
      const float4 b = *(const float4*)wp;
      Ws[lk + 0][lrow] = b.x;
      Ws[lk + 1][lrow] = b.y;
      Ws[lk + 2][lrow] = b.z;
      Ws[lk + 3][lrow] = b.w;
    }
    __syncthreads();
#pragma unroll
    for (int kk = 0; kk < BK; ++kk) {
      float a[4], b[4];
      *(float4*)a = *(const float4*)&As[kk][ty << 2];
      *(float4*)b = *(const float4*)&Ws[kk][tx << 2];
#pragma unroll
      for (int i = 0; i < 4; ++i)
#pragma unroll
        for (int j = 0; j < 4; ++j) acc[i][j] = fmaf(a[i], b[j], acc[i][j]);
    }
    __syncthreads();
  }

  const int mo = m0 + (ty << 2);
  const int no = n0 + (tx << 2);
#pragma unroll
  for (int i = 0; i < 4; ++i) {
    const float4 r = make_float4(acc[i][0], acc[i][1], acc[i][2], acc[i][3]);
    *(float4*)(out + (size_t)(mo + i) * C_ + no) = r;
  }
}

// ---------------------------------------------------------------------------
// WKV recurrence (numerically stable, exactly the reference math), fused with
// sigmoid(r)*y.  One thread per (b,c) channel, sequential over t.
// zout aliases kin (k[idx] is read before z[idx] is written by the same
// thread) -- so no __restrict__ on those two.
// ---------------------------------------------------------------------------
__global__ __launch_bounds__(256) void wkv_sig(const float* kin,
                                               const float* __restrict__ vin,
                                               const float* __restrict__ rin,
                                               const float* __restrict__ wdec,
                                               const float* __restrict__ ufirst,
                                               float* zout) {
  const int cgrp = blockIdx.x % (C_ / 256);
  const int b = blockIdx.x / (C_ / 256);
  const int c = cgrp * 256 + threadIdx.x;
  const float w = wdec[c];
  const float u = ufirst[c];

  size_t idx = (size_t)b * T_ * C_ + c;
  float p = 0.f, q = 0.f, o = -1e38f;
#pragma unroll 4
  for (int t = 0; t < T_; ++t, idx += C_) {
    const float kt = kin[idx];
    const float vt = vin[idx];
    const float rt = rin[idx];

    const float no = fmaxf(o, u + kt);
    const float Ae = expf(o - no);
    const float Be = expf(u + kt - no);
    const float y = (Ae * p + Be * vt) / (Ae * q + Be);

    const float no2 = fmaxf(w + o, kt);
    const float A2 = expf(w + o - no2);
    const float B2 = expf(kt - no2);
    p = A2 * p + B2 * vt;
    q = A2 * q + B2;
    o = no2;

    const float sr = 1.f / (1.f + expf(-rt));
    zout[idx] = sr * y;
  }
}

// ---------------------------------------------------------------------------
extern "C" void kernel_launch(void* const* d_in, const int* in_sizes, int n_in,
                              void* d_out, int out_size, void* d_ws,
                              size_t ws_size, hipStream_t stream) {
  const float* x   = (const float*)d_in[0];
  const float* td  = (const float*)d_in[1];
  const float* tf  = (const float*)d_in[2];
  const float* tmk = (const float*)d_in[3];
  const float* tmv = (const float*)d_in[4];
  const float* tmr = (const float*)d_in[5];
  const float* Wk  = (const float*)d_in[6];
  const float* Wv  = (const float*)d_in[7];
  const float* Wr  = (const float*)d_in[8];
  const float* Wo  = (const float*)d_in[9];
  float* out = (float*)d_out;

  const size_t n = (size_t)M_ * C_;  // 25.17M elements, 96 MiB each
  float* kbuf = (float*)d_ws;
  float* vbuf = kbuf + n;
  float* rbuf = vbuf + n;  // total 288 MiB of d_ws

  dim3 grid(M_ / BM, C_ / BN);
  dim3 blk(256);

  gemm_bt<1><<<grid, blk, 0, stream>>>(x, Wk, tmk, kbuf);
  gemm_bt<1><<<grid, blk, 0, stream>>>(x, Wv, tmv, vbuf);
  gemm_bt<1><<<grid, blk, 0, stream>>>(x, Wr, tmr, rbuf);

  // z = sigmoid(r) * wkv(k, v); z overwrites kbuf in place
  wkv_sig<<<B_ * (C_ / 256), 256, 0, stream>>>(kbuf, vbuf, rbuf, td, tf, kbuf);

  gemm_bt<0><<<grid, blk, 0, stream>>>(kbuf, Wo, nullptr, out);
}

// Round 2
// 534.443 us; speedup vs baseline: 5.4258x; 5.4258x over previous
//
#include <hip/hip_runtime.h>
#include <math.h>

#define B_ 32
#define T_ 1024
#define C_ 768
#define M_ (B_ * T_)   // 32768

typedef __attribute__((ext_vector_type(8))) short bf16x8;
typedef __attribute__((ext_vector_type(4))) float f32x4;
typedef __attribute__((ext_vector_type(8))) unsigned short u16x8;
typedef __attribute__((address_space(1))) const void g_void;
typedef __attribute__((address_space(3))) void lds_void;

__device__ __forceinline__ unsigned short f2bf(float f) {
  union { float f; unsigned int u; } v; v.f = f;
  unsigned int u = v.u;
  u += 0x7fffu + ((u >> 16) & 1u);   // RNE
  return (unsigned short)(u >> 16);
}

// ---------------------------------------------------------------------------
// x (f32) + time-shift mix -> bf16 matrix
// ---------------------------------------------------------------------------
__global__ __launch_bounds__(256) void mix_bf16(const float* __restrict__ x,
                                                const float* __restrict__ tm,
                                                unsigned short* __restrict__ out) {
  const unsigned int gi = blockIdx.x * 256u + threadIdx.x;  // group of 8 elems
  const int m = gi / (C_ / 8);
  const int c8 = (gi % (C_ / 8)) * 8;
  const float* xp = x + (size_t)m * C_ + c8;
  float xv[8], xxv[8], tv[8];
  *(float4*)&xv[0] = *(const float4*)xp;
  *(float4*)&xv[4] = *(const float4*)(xp + 4);
  if ((m & (T_ - 1)) != 0) {
    *(float4*)&xxv[0] = *(const float4*)(xp - C_);
    *(float4*)&xxv[4] = *(const float4*)(xp - C_ + 4);
  } else {
#pragma unroll
    for (int i = 0; i < 8; ++i) xxv[i] = 0.f;
  }
  *(float4*)&tv[0] = *(const float4*)(tm + c8);
  *(float4*)&tv[4] = *(const float4*)(tm + c8 + 4);
  u16x8 o;
#pragma unroll
  for (int i = 0; i < 8; ++i) o[i] = f2bf(xv[i] * tv[i] + xxv[i] * (1.f - tv[i]));
  *(u16x8*)(out + (size_t)m * C_ + c8) = o;
}

// f32 -> bf16 (weights)
__global__ __launch_bounds__(256) void cvt_bf16(const float* __restrict__ in,
                                                unsigned short* __restrict__ out, int n8) {
  const int gi = blockIdx.x * 256 + threadIdx.x;
  if (gi >= n8) return;
  const float* p = in + (size_t)gi * 8;
  float v[8];
  *(float4*)&v[0] = *(const float4*)p;
  *(float4*)&v[4] = *(const float4*)(p + 4);
  u16x8 o;
#pragma unroll
  for (int i = 0; i < 8; ++i) o[i] = f2bf(v[i]);
  *(u16x8*)(out + (size_t)gi * 8) = o;
}

// ---------------------------------------------------------------------------
// bf16 GEMM (m97 structure): out[m][n] = sum_k A[m][k] * W[n][k], f32 out.
// 128x128 tile, BK=64, 4 waves (2x2 of 64x64), mfma_f32_16x16x32_bf16.
// ---------------------------------------------------------------------------
#define BM 128
#define BN 128
#define BK 64
#define NBLK ((M_ / BM) * (C_ / BN))   // 256*6 = 1536

__global__ __launch_bounds__(256) void gemm_bf16(const unsigned short* __restrict__ A,
                                                 const unsigned short* __restrict__ W,
                                                 float* __restrict__ out) {
  __shared__ unsigned short As[BM * BK];  // [128][64] row-major
  __shared__ unsigned short Bs[BN * BK];

  // bijective XCD-aware swizzle (1536 % 8 == 0)
  int bid = (int)blockIdx.x;
  bid = (bid & 7) * (NBLK / 8) + (bid >> 3);
  const int mt = bid / (C_ / BN);
  const int nt = bid % (C_ / BN);
  const int m0 = mt * BM, n0 = nt * BN;

  const int tid = threadIdx.x;
  const int lane = tid & 63;
  const int wv = tid >> 6;        // wave 0..3
  const int wm = wv >> 1, wn = wv & 1;

  // staging: per round r (0..3), wave wv covers LDS bytes r*4096 + wv*1024 + lane*16
  // -> row = r*32 + wv*8 + lane/8, col elems = (lane&7)*8
  const unsigned short* abase =
      A + (size_t)(m0 + wv * 8 + (lane >> 3)) * C_ + (lane & 7) * 8;
  const unsigned short* wbase =
      W + (size_t)(n0 + wv * 8 + (lane >> 3)) * C_ + (lane & 7) * 8;

  f32x4 acc[4][4] = {};

  for (int k0 = 0; k0 < C_; k0 += BK) {
#pragma unroll
    for (int r = 0; r < 4; ++r) {
      __builtin_amdgcn_global_load_lds((g_void*)(abase + (size_t)r * 32 * C_ + k0),
                                       (lds_void*)&As[r * 2048 + wv * 512], 16, 0, 0);
      __builtin_amdgcn_global_load_lds((g_void*)(wbase + (size_t)r * 32 * C_ + k0),
                                       (lds_void*)&Bs[r * 2048 + wv * 512], 16, 0, 0);
    }
    __syncthreads();
#pragma unroll
    for (int kk = 0; kk < BK; kk += 32) {
      bf16x8 af[4], bfv[4];
#pragma unroll
      for (int f = 0; f < 4; ++f) {
        af[f] = *(const bf16x8*)&As[(wm * 64 + f * 16 + (lane & 15)) * BK + kk + (lane >> 4) * 8];
        bfv[f] = *(const bf16x8*)&Bs[(wn * 64 + f * 16 + (lane & 15)) * BK + kk + (lane >> 4) * 8];
      }
#pragma unroll
      for (int i = 0; i < 4; ++i)
#pragma unroll
        for (int j = 0; j < 4; ++j)
          acc[i][j] = __builtin_amdgcn_mfma_f32_16x16x32_bf16(af[i], bfv[j], acc[i][j], 0, 0, 0);
    }
    __syncthreads();
  }

  // C/D layout: col = lane&15, row = (lane>>4)*4 + reg  (m89-verified)
  const int crow0 = m0 + wm * 64 + (lane >> 4) * 4;
  const int ccol0 = n0 + wn * 64 + (lane & 15);
#pragma unroll
  for (int i = 0; i < 4; ++i)
#pragma unroll
    for (int j = 0; j < 4; ++j)
#pragma unroll
      for (int r = 0; r < 4; ++r)
        out[(size_t)(crow0 + i * 16 + r) * C_ + ccol0 + j * 16] = acc[i][j][r];
}

// ---------------------------------------------------------------------------
// WKV recurrence + sigmoid(r)*y, bf16 output. De-aliased, software-pipelined.
// One thread per (b,c); 64-thread blocks spread across CUs.
// ---------------------------------------------------------------------------
#define WU 8

__device__ __forceinline__ void loadc(const float* __restrict__ kin,
                                      const float* __restrict__ vin,
                                      const float* __restrict__ rin, size_t base,
                                      float* k, float* v, float* r) {
#pragma unroll
  for (int i = 0; i < WU; ++i) {
    k[i] = kin[base + (size_t)i * C_];
    v[i] = vin[base + (size_t)i * C_];
    r[i] = rin[base + (size_t)i * C_];
  }
}

__device__ __forceinline__ void compc(const float* k, const float* v, const float* r,
                                      float w, float u, float& p, float& q, float& o,
                                      unsigned short* __restrict__ z, size_t base) {
#pragma unroll
  for (int i = 0; i < WU; ++i) {
    const float kt = k[i], vt = v[i], rt = r[i];
    const float no = fmaxf(o, u + kt);
    const float Ae = __expf(o - no);
    const float Be = __expf(u + kt - no);
    const float y = (Ae * p + Be * vt) / (Ae * q + Be);
    const float no2 = fmaxf(w + o, kt);
    const float A2 = __expf(w + o - no2);
    const float B2 = __expf(kt - no2);
    p = A2 * p + B2 * vt;
    q = A2 * q + B2;
    o = no2;
    const float sr = 1.f / (1.f + __expf(-rt));
    z[base + (size_t)i * C_] = f2bf(sr * y);
  }
}

__global__ __launch_bounds__(64) void wkv_sig(const float* __restrict__ kin,
                                              const float* __restrict__ vin,
                                              const float* __restrict__ rin,
                                              const float* __restrict__ wdec,
                                              const float* __restrict__ ufirst,
                                              unsigned short* __restrict__ z) {
  const int b = blockIdx.x / (C_ / 64);
  const int c = (blockIdx.x % (C_ / 64)) * 64 + threadIdx.x;
  const float w = wdec[c], u = ufirst[c];
  size_t idx = (size_t)b * T_ * C_ + c;

  float kA[WU], vA[WU], rA[WU], kB[WU], vB[WU], rB[WU];
  float p = 0.f, q = 0.f, o = -1e38f;
  const size_t step = (size_t)WU * C_;

  loadc(kin, vin, rin, idx, kA, vA, rA);
  for (int j = 0; j < T_ / (2 * WU); ++j) {
    loadc(kin, vin, rin, idx + step, kB, vB, rB);
    compc(kA, vA, rA, w, u, p, q, o, z, idx);
    if (j < T_ / (2 * WU) - 1) loadc(kin, vin, rin, idx + 2 * step, kA, vA, rA);
    compc(kB, vB, rB, w, u, p, q, o, z, idx + step);
    idx += 2 * step;
  }
}

// ---------------------------------------------------------------------------
extern "C" void kernel_launch(void* const* d_in, const int* in_sizes, int n_in,
                              void* d_out, int out_size, void* d_ws,
                              size_t ws_size, hipStream_t stream) {
  const float* x   = (const float*)d_in[0];
  const float* td  = (const float*)d_in[1];
  const float* tf  = (const float*)d_in[2];
  const float* tmk = (const float*)d_in[3];
  const float* tmv = (const float*)d_in[4];
  const float* tmr = (const float*)d_in[5];
  const float* Wk  = (const float*)d_in[6];
  const float* Wv  = (const float*)d_in[7];
  const float* Wr  = (const float*)d_in[8];
  const float* Wo  = (const float*)d_in[9];

  const size_t nW = (size_t)C_ * C_;          // 589824
  const size_t nM = (size_t)M_ * C_;          // 25165824

  // ws layout (244.5 MiB total): 4 bf16 weights | xbuf bf16 (reused as z) | k f32 | v f32
  unsigned short* wbk = (unsigned short*)d_ws;
  unsigned short* wbv = wbk + nW;
  unsigned short* wbr = wbv + nW;
  unsigned short* wbo = wbr + nW;
  unsigned short* xb  = wbo + nW;
  float* kbuf = (float*)(xb + nM);
  float* vbuf = kbuf + nM;
  unsigned short* zb = xb;        // reuse: xb dead after gemm_r
  float* rbuf = (float*)d_out;    // r lives in d_out, consumed before final GEMM

  const int wgrid = (int)(nW / 8 / 256);      // 288
  cvt_bf16<<<wgrid, 256, 0, stream>>>(Wk, wbk, (int)(nW / 8));
  cvt_bf16<<<wgrid, 256, 0, stream>>>(Wv, wbv, (int)(nW / 8));
  cvt_bf16<<<wgrid, 256, 0, stream>>>(Wr, wbr, (int)(nW / 8));
  cvt_bf16<<<wgrid, 256, 0, stream>>>(Wo, wbo, (int)(nW / 8));

  const int mgrid = (int)(nM / 8 / 256);      // 12288
  mix_bf16<<<mgrid, 256, 0, stream>>>(x, tmk, xb);
  gemm_bf16<<<NBLK, 256, 0, stream>>>(xb, wbk, kbuf);
  mix_bf16<<<mgrid, 256, 0, stream>>>(x, tmv, xb);
  gemm_bf16<<<NBLK, 256, 0, stream>>>(xb, wbv, vbuf);
  mix_bf16<<<mgrid, 256, 0, stream>>>(x, tmr, xb);
  gemm_bf16<<<NBLK, 256, 0, stream>>>(xb, wbr, rbuf);

  wkv_sig<<<B_ * (C_ / 64), 64, 0, stream>>>(kbuf, vbuf, rbuf, td, tf, zb);

  gemm_bf16<<<NBLK, 256, 0, stream>>>(zb, wbo, (float*)d_out);
}

// Round 3
// 485.159 us; speedup vs baseline: 5.9770x; 1.1016x over previous
//
#include <hip/hip_runtime.h>
#include <math.h>

#define B_ 32
#define T_ 1024
#define C_ 768
#define M_ (B_ * T_)   // 32768

typedef __attribute__((ext_vector_type(8))) short bf16x8;
typedef __attribute__((ext_vector_type(4))) float f32x4;
typedef __attribute__((ext_vector_type(8))) unsigned short u16x8;
typedef __attribute__((address_space(1))) const void g_void;
typedef __attribute__((address_space(3))) void lds_void;

__device__ __forceinline__ unsigned short f2bf(float f) {
  union { float f; unsigned int u; } v; v.f = f;
  unsigned int u = v.u;
  u += 0x7fffu + ((u >> 16) & 1u);   // RNE
  return (unsigned short)(u >> 16);
}

// ---------------------------------------------------------------------------
// Fused time-shift mix: read x once, emit xk, xv, xr (bf16)
// ---------------------------------------------------------------------------
__global__ __launch_bounds__(256) void mix3_bf16(const float* __restrict__ x,
                                                 const float* __restrict__ tmk,
                                                 const float* __restrict__ tmv,
                                                 const float* __restrict__ tmr,
                                                 unsigned short* __restrict__ ok,
                                                 unsigned short* __restrict__ ov,
                                                 unsigned short* __restrict__ orr) {
  const unsigned int gi = blockIdx.x * 256u + threadIdx.x;  // group of 8 elems
  const int m = gi / (C_ / 8);
  const int c8 = (gi % (C_ / 8)) * 8;
  const float* xp = x + (size_t)m * C_ + c8;
  float xv8[8], xx8[8], t8[8];
  *(float4*)&xv8[0] = *(const float4*)xp;
  *(float4*)&xv8[4] = *(const float4*)(xp + 4);
  if ((m & (T_ - 1)) != 0) {
    *(float4*)&xx8[0] = *(const float4*)(xp - C_);
    *(float4*)&xx8[4] = *(const float4*)(xp - C_ + 4);
  } else {
#pragma unroll
    for (int i = 0; i < 8; ++i) xx8[i] = 0.f;
  }
  const size_t ob = (size_t)m * C_ + c8;

  *(float4*)&t8[0] = *(const float4*)(tmk + c8);
  *(float4*)&t8[4] = *(const float4*)(tmk + c8 + 4);
  u16x8 o;
#pragma unroll
  for (int i = 0; i < 8; ++i) o[i] = f2bf(xv8[i] * t8[i] + xx8[i] * (1.f - t8[i]));
  *(u16x8*)(ok + ob) = o;

  *(float4*)&t8[0] = *(const float4*)(tmv + c8);
  *(float4*)&t8[4] = *(const float4*)(tmv + c8 + 4);
#pragma unroll
  for (int i = 0; i < 8; ++i) o[i] = f2bf(xv8[i] * t8[i] + xx8[i] * (1.f - t8[i]));
  *(u16x8*)(ov + ob) = o;

  *(float4*)&t8[0] = *(const float4*)(tmr + c8);
  *(float4*)&t8[4] = *(const float4*)(tmr + c8 + 4);
#pragma unroll
  for (int i = 0; i < 8; ++i) o[i] = f2bf(xv8[i] * t8[i] + xx8[i] * (1.f - t8[i]));
  *(u16x8*)(orr + ob) = o;
}

// f32 -> bf16 (weights)
__global__ __launch_bounds__(256) void cvt_bf16(const float* __restrict__ in,
                                                unsigned short* __restrict__ out, int n8) {
  const int gi = blockIdx.x * 256 + threadIdx.x;
  if (gi >= n8) return;
  const float* p = in + (size_t)gi * 8;
  float v[8];
  *(float4*)&v[0] = *(const float4*)p;
  *(float4*)&v[4] = *(const float4*)(p + 4);
  u16x8 o;
#pragma unroll
  for (int i = 0; i < 8; ++i) o[i] = f2bf(v[i]);
  *(u16x8*)(out + (size_t)gi * 8) = o;
}

// ---------------------------------------------------------------------------
// bf16 GEMM (m97 structure, unchanged from round 2 -- known good)
// ---------------------------------------------------------------------------
#define BM 128
#define BN 128
#define BK 64
#define NBLK ((M_ / BM) * (C_ / BN))   // 1536

__global__ __launch_bounds__(256) void gemm_bf16(const unsigned short* __restrict__ A,
                                                 const unsigned short* __restrict__ W,
                                                 float* __restrict__ out) {
  __shared__ unsigned short As[BM * BK];
  __shared__ unsigned short Bs[BN * BK];

  int bid = (int)blockIdx.x;
  bid = (bid & 7) * (NBLK / 8) + (bid >> 3);
  const int mt = bid / (C_ / BN);
  const int nt = bid % (C_ / BN);
  const int m0 = mt * BM, n0 = nt * BN;

  const int tid = threadIdx.x;
  const int lane = tid & 63;
  const int wv = tid >> 6;
  const int wm = wv >> 1, wn = wv & 1;

  const unsigned short* abase =
      A + (size_t)(m0 + wv * 8 + (lane >> 3)) * C_ + (lane & 7) * 8;
  const unsigned short* wbase =
      W + (size_t)(n0 + wv * 8 + (lane >> 3)) * C_ + (lane & 7) * 8;

  f32x4 acc[4][4] = {};

  for (int k0 = 0; k0 < C_; k0 += BK) {
#pragma unroll
    for (int r = 0; r < 4; ++r) {
      __builtin_amdgcn_global_load_lds((g_void*)(abase + (size_t)r * 32 * C_ + k0),
                                       (lds_void*)&As[r * 2048 + wv * 512], 16, 0, 0);
      __builtin_amdgcn_global_load_lds((g_void*)(wbase + (size_t)r * 32 * C_ + k0),
                                       (lds_void*)&Bs[r * 2048 + wv * 512], 16, 0, 0);
    }
    __syncthreads();
#pragma unroll
    for (int kk = 0; kk < BK; kk += 32) {
      bf16x8 af[4], bfv[4];
#pragma unroll
      for (int f = 0; f < 4; ++f) {
        af[f] = *(const bf16x8*)&As[(wm * 64 + f * 16 + (lane & 15)) * BK + kk + (lane >> 4) * 8];
        bfv[f] = *(const bf16x8*)&Bs[(wn * 64 + f * 16 + (lane & 15)) * BK + kk + (lane >> 4) * 8];
      }
#pragma unroll
      for (int i = 0; i < 4; ++i)
#pragma unroll
        for (int j = 0; j < 4; ++j)
          acc[i][j] = __builtin_amdgcn_mfma_f32_16x16x32_bf16(af[i], bfv[j], acc[i][j], 0, 0, 0);
    }
    __syncthreads();
  }

  const int crow0 = m0 + wm * 64 + (lane >> 4) * 4;
  const int ccol0 = n0 + wn * 64 + (lane & 15);
#pragma unroll
  for (int i = 0; i < 4; ++i)
#pragma unroll
    for (int j = 0; j < 4; ++j)
#pragma unroll
      for (int r = 0; r < 4; ++r)
        out[(size_t)(crow0 + i * 16 + r) * C_ + ccol0 + j * 16] = acc[i][j][r];
}

// ---------------------------------------------------------------------------
// WKV via chunked associative scan over T.
// Block: NCH=16 chunks x CGRP=32 channels = 512 threads. Grid: 32*24 = 768.
// Phase 1: local scan of 64 steps (state p,q,o from neutral).
// Phase 2: Kogge-Stone prefix combine in LDS (4 steps; right-span = s*CL).
// Phase 3: re-scan emitting z = sigmoid(r)*y from exclusive prefix state.
// ---------------------------------------------------------------------------
#define NCH 16
#define CL  (T_ / NCH)   // 64
#define CGRP 32

__global__ __launch_bounds__(512) void wkv_scan(const float* __restrict__ kin,
                                                const float* __restrict__ vin,
                                                const float* __restrict__ rin,
                                                const float* __restrict__ wdec,
                                                const float* __restrict__ ufirst,
                                                unsigned short* __restrict__ z) {
  __shared__ float ps[NCH][CGRP], qs[NCH][CGRP], os[NCH][CGRP];

  const int b = blockIdx.x / (C_ / CGRP);
  const int cg = blockIdx.x % (C_ / CGRP);
  const int ci = threadIdx.x & (CGRP - 1);
  const int j = threadIdx.x / CGRP;          // chunk 0..15
  const int c = cg * CGRP + ci;
  const float w = wdec[c], u = ufirst[c];
  const size_t base = ((size_t)b * T_ + (size_t)j * CL) * C_ + c;

  // ---- phase 1: local chunk scan (state only) ----
  float p = 0.f, q = 0.f, o = -1e38f;
  {
    size_t idx = base;
#pragma unroll 4
    for (int t = 0; t < CL; ++t, idx += C_) {
      const float kt = kin[idx], vt = vin[idx];
      const float no2 = fmaxf(w + o, kt);
      const float A2 = __expf(w + o - no2);
      const float B2 = __expf(kt - no2);
      p = A2 * p + B2 * vt;
      q = A2 * q + B2;
      o = no2;
    }
  }
  ps[j][ci] = p; qs[j][ci] = q; os[j][ci] = o;
  __syncthreads();

  // ---- phase 2: Kogge-Stone inclusive scan over chunks ----
#pragma unroll
  for (int s = 1; s < NCH; s <<= 1) {
    float P = p, Q = q, O = o;
    if (j >= s) {
      const float lp = ps[j - s][ci], lq = qs[j - s][ci], lo = os[j - s][ci];
      const float d = w * (float)(s * CL) + lo;   // left state decayed across right span
      const float no = fmaxf(d, o);
      const float ea = __expf(d - no), eb = __expf(o - no);
      P = ea * lp + eb * p;
      Q = ea * lq + eb * q;
      O = no;
    }
    __syncthreads();
    p = P; q = Q; o = O;
    ps[j][ci] = p; qs[j][ci] = q; os[j][ci] = o;
    __syncthreads();
  }

  // ---- phase 3: re-scan with exclusive prefix, emit z ----
  float pp = 0.f, qq = 0.f, oo = -1e38f;
  if (j > 0) { pp = ps[j - 1][ci]; qq = qs[j - 1][ci]; oo = os[j - 1][ci]; }

  size_t idx = base;
#pragma unroll 4
  for (int t = 0; t < CL; ++t, idx += C_) {
    const float kt = kin[idx], vt = vin[idx], rt = rin[idx];

    const float no = fmaxf(oo, u + kt);
    const float Ae = __expf(oo - no);
    const float Be = __expf(u + kt - no);
    const float y = __fdividef(Ae * pp + Be * vt, Ae * qq + Be);

    const float no2 = fmaxf(w + oo, kt);
    const float A2 = __expf(w + oo - no2);
    const float B2 = __expf(kt - no2);
    pp = A2 * pp + B2 * vt;
    qq = A2 * qq + B2;
    oo = no2;

    const float sr = __fdividef(1.f, 1.f + __expf(-rt));
    z[idx] = f2bf(sr * y);
  }
}

// ---------------------------------------------------------------------------
extern "C" void kernel_launch(void* const* d_in, const int* in_sizes, int n_in,
                              void* d_out, int out_size, void* d_ws,
                              size_t ws_size, hipStream_t stream) {
  const float* x   = (const float*)d_in[0];
  const float* td  = (const float*)d_in[1];
  const float* tf  = (const float*)d_in[2];
  const float* tmk = (const float*)d_in[3];
  const float* tmv = (const float*)d_in[4];
  const float* tmr = (const float*)d_in[5];
  const float* Wk  = (const float*)d_in[6];
  const float* Wv  = (const float*)d_in[7];
  const float* Wr  = (const float*)d_in[8];
  const float* Wo  = (const float*)d_in[9];

  const size_t nW = (size_t)C_ * C_;
  const size_t nM = (size_t)M_ * C_;

  // ws layout (244.5 MiB):
  //  [wbk wbv wbr wbo : bf16 4x1.125MiB][xv 48][xr 48][xk 48][kbuf f32 96]
  //  vbuf (f32 96) overlays xr+xk after they die; z (bf16 48) overlays xv.
  unsigned short* wbk = (unsigned short*)d_ws;
  unsigned short* wbv = wbk + nW;
  unsigned short* wbr = wbv + nW;
  unsigned short* wbo = wbr + nW;
  unsigned short* xv  = wbo + nW;
  unsigned short* xr  = xv + nM;
  unsigned short* xk  = xr + nM;
  float* kbuf = (float*)(xk + nM);
  float* vbuf = (float*)xr;       // overlays xr+xk (both dead by then)
  unsigned short* zb = xv;        // overlays xv (dead after gemm_v)
  float* rbuf = (float*)d_out;    // r lives in d_out, consumed before final GEMM

  const int wgrid = (int)(nW / 8 / 256);
  cvt_bf16<<<wgrid, 256, 0, stream>>>(Wk, wbk, (int)(nW / 8));
  cvt_bf16<<<wgrid, 256, 0, stream>>>(Wv, wbv, (int)(nW / 8));
  cvt_bf16<<<wgrid, 256, 0, stream>>>(Wr, wbr, (int)(nW / 8));
  cvt_bf16<<<wgrid, 256, 0, stream>>>(Wo, wbo, (int)(nW / 8));

  const int mgrid = (int)(nM / 8 / 256);
  mix3_bf16<<<mgrid, 256, 0, stream>>>(x, tmk, tmv, tmr, xk, xv, xr);

  gemm_bf16<<<NBLK, 256, 0, stream>>>(xr, wbr, rbuf);   // r -> d_out      (xr dies)
  gemm_bf16<<<NBLK, 256, 0, stream>>>(xk, wbk, kbuf);   // k -> kbuf       (xk dies)
  gemm_bf16<<<NBLK, 256, 0, stream>>>(xv, wbv, vbuf);   // v -> xr+xk area (xv dies)

  wkv_scan<<<B_ * (C_ / CGRP), 512, 0, stream>>>(kbuf, vbuf, rbuf, td, tf, zb);

  gemm_bf16<<<NBLK, 256, 0, stream>>>(zb, wbo, (float*)d_out);
}

// Round 4
// 406.183 us; speedup vs baseline: 7.1391x; 1.1944x over previous
//
#include <hip/hip_runtime.h>
#include <math.h>

#define B_ 32
#define T_ 1024
#define C_ 768
#define M_ (B_ * T_)   // 32768

typedef __attribute__((ext_vector_type(8))) short bf16x8;
typedef __attribute__((ext_vector_type(4))) float f32x4;
typedef __attribute__((ext_vector_type(8))) unsigned short u16x8;
typedef __attribute__((address_space(1))) const void g_void;
typedef __attribute__((address_space(3))) void lds_void;

__device__ __forceinline__ unsigned short f2bf(float f) {
  union { float f; unsigned int u; } v; v.f = f;
  unsigned int u = v.u;
  u += 0x7fffu + ((u >> 16) & 1u);   // RNE
  return (unsigned short)(u >> 16);
}
__device__ __forceinline__ float b2f(unsigned short h) {
  union { unsigned int u; float f; } v; v.u = ((unsigned int)h) << 16;
  return v.f;
}

// ---------------------------------------------------------------------------
// Fused time-shift mix: read x once, emit xk, xv, xr (bf16)
// ---------------------------------------------------------------------------
__global__ __launch_bounds__(256) void mix3_bf16(const float* __restrict__ x,
                                                 const float* __restrict__ tmk,
                                                 const float* __restrict__ tmv,
                                                 const float* __restrict__ tmr,
                                                 unsigned short* __restrict__ ok,
                                                 unsigned short* __restrict__ ov,
                                                 unsigned short* __restrict__ orr) {
  const unsigned int gi = blockIdx.x * 256u + threadIdx.x;  // group of 8 elems
  const int m = gi / (C_ / 8);
  const int c8 = (gi % (C_ / 8)) * 8;
  const float* xp = x + (size_t)m * C_ + c8;
  float xv8[8], xx8[8], t8[8];
  *(float4*)&xv8[0] = *(const float4*)xp;
  *(float4*)&xv8[4] = *(const float4*)(xp + 4);
  if ((m & (T_ - 1)) != 0) {
    *(float4*)&xx8[0] = *(const float4*)(xp - C_);
    *(float4*)&xx8[4] = *(const float4*)(xp - C_ + 4);
  } else {
#pragma unroll
    for (int i = 0; i < 8; ++i) xx8[i] = 0.f;
  }
  const size_t ob = (size_t)m * C_ + c8;

  *(float4*)&t8[0] = *(const float4*)(tmk + c8);
  *(float4*)&t8[4] = *(const float4*)(tmk + c8 + 4);
  u16x8 o;
#pragma unroll
  for (int i = 0; i < 8; ++i) o[i] = f2bf(xv8[i] * t8[i] + xx8[i] * (1.f - t8[i]));
  *(u16x8*)(ok + ob) = o;

  *(float4*)&t8[0] = *(const float4*)(tmv + c8);
  *(float4*)&t8[4] = *(const float4*)(tmv + c8 + 4);
#pragma unroll
  for (int i = 0; i < 8; ++i) o[i] = f2bf(xv8[i] * t8[i] + xx8[i] * (1.f - t8[i]));
  *(u16x8*)(ov + ob) = o;

  *(float4*)&t8[0] = *(const float4*)(tmr + c8);
  *(float4*)&t8[4] = *(const float4*)(tmr + c8 + 4);
#pragma unroll
  for (int i = 0; i < 8; ++i) o[i] = f2bf(xv8[i] * t8[i] + xx8[i] * (1.f - t8[i]));
  *(u16x8*)(orr + ob) = o;
}

// f32 -> bf16 for all 4 weight matrices in one launch (blockIdx.y selects)
__global__ __launch_bounds__(256) void cvt4_bf16(const float* __restrict__ s0,
                                                 const float* __restrict__ s1,
                                                 const float* __restrict__ s2,
                                                 const float* __restrict__ s3,
                                                 unsigned short* __restrict__ d0,
                                                 unsigned short* __restrict__ d1,
                                                 unsigned short* __restrict__ d2,
                                                 unsigned short* __restrict__ d3) {
  const float* src = (blockIdx.y == 0) ? s0 : (blockIdx.y == 1) ? s1
                     : (blockIdx.y == 2) ? s2 : s3;
  unsigned short* dst = (blockIdx.y == 0) ? d0 : (blockIdx.y == 1) ? d1
                        : (blockIdx.y == 2) ? d2 : d3;
  const int gi = blockIdx.x * 256 + threadIdx.x;
  const float* p = src + (size_t)gi * 8;
  float v[8];
  *(float4*)&v[0] = *(const float4*)p;
  *(float4*)&v[4] = *(const float4*)(p + 4);
  u16x8 o;
#pragma unroll
  for (int i = 0; i < 8; ++i) o[i] = f2bf(v[i]);
  *(u16x8*)(dst + (size_t)gi * 8) = o;
}

// ---------------------------------------------------------------------------
// bf16 GEMM (m97 structure), templated output dtype:
// OUT_BF16=1 -> u16 bf16 output, OUT_BF16=0 -> f32 output
// ---------------------------------------------------------------------------
#define BM 128
#define BN 128
#define BK 64
#define NBLK ((M_ / BM) * (C_ / BN))   // 1536

template <int OUT_BF16>
__global__ __launch_bounds__(256) void gemm_bf16(const unsigned short* __restrict__ A,
                                                 const unsigned short* __restrict__ W,
                                                 void* __restrict__ outv) {
  __shared__ unsigned short As[BM * BK];
  __shared__ unsigned short Bs[BN * BK];

  int bid = (int)blockIdx.x;
  bid = (bid & 7) * (NBLK / 8) + (bid >> 3);
  const int mt = bid / (C_ / BN);
  const int nt = bid % (C_ / BN);
  const int m0 = mt * BM, n0 = nt * BN;

  const int tid = threadIdx.x;
  const int lane = tid & 63;
  const int wv = tid >> 6;
  const int wm = wv >> 1, wn = wv & 1;

  const unsigned short* abase =
      A + (size_t)(m0 + wv * 8 + (lane >> 3)) * C_ + (lane & 7) * 8;
  const unsigned short* wbase =
      W + (size_t)(n0 + wv * 8 + (lane >> 3)) * C_ + (lane & 7) * 8;

  f32x4 acc[4][4] = {};

  for (int k0 = 0; k0 < C_; k0 += BK) {
#pragma unroll
    for (int r = 0; r < 4; ++r) {
      __builtin_amdgcn_global_load_lds((g_void*)(abase + (size_t)r * 32 * C_ + k0),
                                       (lds_void*)&As[r * 2048 + wv * 512], 16, 0, 0);
      __builtin_amdgcn_global_load_lds((g_void*)(wbase + (size_t)r * 32 * C_ + k0),
                                       (lds_void*)&Bs[r * 2048 + wv * 512], 16, 0, 0);
    }
    __syncthreads();
#pragma unroll
    for (int kk = 0; kk < BK; kk += 32) {
      bf16x8 af[4], bfv[4];
#pragma unroll
      for (int f = 0; f < 4; ++f) {
        af[f] = *(const bf16x8*)&As[(wm * 64 + f * 16 + (lane & 15)) * BK + kk + (lane >> 4) * 8];
        bfv[f] = *(const bf16x8*)&Bs[(wn * 64 + f * 16 + (lane & 15)) * BK + kk + (lane >> 4) * 8];
      }
#pragma unroll
      for (int i = 0; i < 4; ++i)
#pragma unroll
        for (int j = 0; j < 4; ++j)
          acc[i][j] = __builtin_amdgcn_mfma_f32_16x16x32_bf16(af[i], bfv[j], acc[i][j], 0, 0, 0);
    }
    __syncthreads();
  }

  // C/D layout: col = lane&15, row = (lane>>4)*4 + reg  (m89-verified)
  const int crow0 = m0 + wm * 64 + (lane >> 4) * 4;
  const int ccol0 = n0 + wn * 64 + (lane & 15);
  if (OUT_BF16) {
    unsigned short* out = (unsigned short*)outv;
#pragma unroll
    for (int i = 0; i < 4; ++i)
#pragma unroll
      for (int j = 0; j < 4; ++j)
#pragma unroll
        for (int r = 0; r < 4; ++r)
          out[(size_t)(crow0 + i * 16 + r) * C_ + ccol0 + j * 16] = f2bf(acc[i][j][r]);
  } else {
    float* out = (float*)outv;
#pragma unroll
    for (int i = 0; i < 4; ++i)
#pragma unroll
      for (int j = 0; j < 4; ++j)
#pragma unroll
        for (int r = 0; r < 4; ++r)
          out[(size_t)(crow0 + i * 16 + r) * C_ + ccol0 + j * 16] = acc[i][j][r];
  }
}

// ---------------------------------------------------------------------------
// WKV chunked associative scan (bf16 inputs k,v,r; bf16 output z).
// Block: NCH=16 chunks x CGRP=32 channels = 512 threads.
// ---------------------------------------------------------------------------
#define NCH 16
#define CL  (T_ / NCH)   // 64
#define CGRP 32

__global__ __launch_bounds__(512) void wkv_scan(const unsigned short* __restrict__ kin,
                                                const unsigned short* __restrict__ vin,
                                                const unsigned short* __restrict__ rin,
                                                const float* __restrict__ wdec,
                                                const float* __restrict__ ufirst,
                                                unsigned short* __restrict__ z) {
  __shared__ float ps[NCH][CGRP], qs[NCH][CGRP], os[NCH][CGRP];

  const int b = blockIdx.x / (C_ / CGRP);
  const int cg = blockIdx.x % (C_ / CGRP);
  const int ci = threadIdx.x & (CGRP - 1);
  const int j = threadIdx.x / CGRP;          // chunk 0..15
  const int c = cg * CGRP + ci;
  const float w = wdec[c], u = ufirst[c];
  const size_t base = ((size_t)b * T_ + (size_t)j * CL) * C_ + c;

  // ---- phase 1: local chunk scan (state only) ----
  float p = 0.f, q = 0.f, o = -1e38f;
  {
    size_t idx = base;
#pragma unroll 4
    for (int t = 0; t < CL; ++t, idx += C_) {
      const float kt = b2f(kin[idx]), vt = b2f(vin[idx]);
      const float no2 = fmaxf(w + o, kt);
      const float A2 = __expf(w + o - no2);
      const float B2 = __expf(kt - no2);
      p = A2 * p + B2 * vt;
      q = A2 * q + B2;
      o = no2;
    }
  }
  ps[j][ci] = p; qs[j][ci] = q; os[j][ci] = o;
  __syncthreads();

  // ---- phase 2: Kogge-Stone inclusive scan over chunks ----
#pragma unroll
  for (int s = 1; s < NCH; s <<= 1) {
    float P = p, Q = q, O = o;
    if (j >= s) {
      const float lp = ps[j - s][ci], lq = qs[j - s][ci], lo = os[j - s][ci];
      const float d = w * (float)(s * CL) + lo;   // left state decayed across span
      const float no = fmaxf(d, o);
      const float ea = __expf(d - no), eb = __expf(o - no);
      P = ea * lp + eb * p;
      Q = ea * lq + eb * q;
      O = no;
    }
    __syncthreads();
    p = P; q = Q; o = O;
    ps[j][ci] = p; qs[j][ci] = q; os[j][ci] = o;
    __syncthreads();
  }

  // ---- phase 3: re-scan with exclusive prefix, emit z ----
  float pp = 0.f, qq = 0.f, oo = -1e38f;
  if (j > 0) { pp = ps[j - 1][ci]; qq = qs[j - 1][ci]; oo = os[j - 1][ci]; }

  size_t idx = base;
#pragma unroll 4
  for (int t = 0; t < CL; ++t, idx += C_) {
    const float kt = b2f(kin[idx]), vt = b2f(vin[idx]), rt = b2f(rin[idx]);

    const float no = fmaxf(oo, u + kt);
    const float Ae = __expf(oo - no);
    const float Be = __expf(u + kt - no);
    const float y = __fdividef(Ae * pp + Be * vt, Ae * qq + Be);

    const float no2 = fmaxf(w + oo, kt);
    const float A2 = __expf(w + oo - no2);
    const float B2 = __expf(kt - no2);
    pp = A2 * pp + B2 * vt;
    qq = A2 * qq + B2;
    oo = no2;

    const float sr = __fdividef(1.f, 1.f + __expf(-rt));
    z[idx] = f2bf(sr * y);
  }
}

// ---------------------------------------------------------------------------
extern "C" void kernel_launch(void* const* d_in, const int* in_sizes, int n_in,
                              void* d_out, int out_size, void* d_ws,
                              size_t ws_size, hipStream_t stream) {
  const float* x   = (const float*)d_in[0];
  const float* td  = (const float*)d_in[1];
  const float* tf  = (const float*)d_in[2];
  const float* tmk = (const float*)d_in[3];
  const float* tmv = (const float*)d_in[4];
  const float* tmr = (const float*)d_in[5];
  const float* Wk  = (const float*)d_in[6];
  const float* Wv  = (const float*)d_in[7];
  const float* Wr  = (const float*)d_in[8];
  const float* Wo  = (const float*)d_in[9];

  const size_t nW = (size_t)C_ * C_;
  const size_t nM = (size_t)M_ * C_;

  // ws layout (244.5 MiB, all bf16):
  //  [wbk wbv wbr wbo][xk 48][xv 48][xr 48][kbuf 48][vbuf 48]
  //  rbuf overlays xk (dead after gemm_k); z overlays xv (dead after gemm_v)
  unsigned short* wbk  = (unsigned short*)d_ws;
  unsigned short* wbv  = wbk + nW;
  unsigned short* wbr  = wbv + nW;
  unsigned short* wbo  = wbr + nW;
  unsigned short* xk   = wbo + nW;
  unsigned short* xv   = xk + nM;
  unsigned short* xr   = xv + nM;
  unsigned short* kbuf = xr + nM;
  unsigned short* vbuf = kbuf + nM;
  unsigned short* rbuf = xk;   // reuse
  unsigned short* zb   = xv;   // reuse

  cvt4_bf16<<<dim3((unsigned)(nW / 8 / 256), 4), 256, 0, stream>>>(
      Wk, Wv, Wr, Wo, wbk, wbv, wbr, wbo);

  const int mgrid = (int)(nM / 8 / 256);
  mix3_bf16<<<mgrid, 256, 0, stream>>>(x, tmk, tmv, tmr, xk, xv, xr);

  gemm_bf16<1><<<NBLK, 256, 0, stream>>>(xk, wbk, kbuf);   // xk dies
  gemm_bf16<1><<<NBLK, 256, 0, stream>>>(xv, wbv, vbuf);   // xv dies
  gemm_bf16<1><<<NBLK, 256, 0, stream>>>(xr, wbr, rbuf);   // -> old xk

  wkv_scan<<<B_ * (C_ / CGRP), 512, 0, stream>>>(kbuf, vbuf, rbuf, td, tf, zb);

  gemm_bf16<0><<<NBLK, 256, 0, stream>>>(zb, wbo, d_out);  // f32 out
}